// Round 1
// baseline (482.899 us; speedup 1.0000x reference)
//
#include <hip/hip_runtime.h>
#include <math.h>

#define B_ 64
#define T_ 2048
#define RNN_DIM 1024
#define EMB_DIM 512
#define ATT_DIM 128
#define N_FILT 32
#define KSIZE 31
#define PAD_ 15
#define TT 64           // t-tile for the energy kernel

__device__ __forceinline__ float fast_tanh(float x) {
    // 1 - 2/(e^{2x}+1); exact at +-inf saturation, ~1e-7 abs err
    float e = __expf(2.0f * x);
    return 1.0f - 2.0f / (e + 1.0f);
}

// ---------------- Kernel A: pq[b,a] = sum_r query[b,r] * Wq[a,r] ----------
__global__ __launch_bounds__(128) void k_pq(const float* __restrict__ query,
                                            const float* __restrict__ Wq,
                                            float* __restrict__ pq) {
    __shared__ float q_s[RNN_DIM];
    const int b = blockIdx.x;
    const int tid = threadIdx.x; // 128
    #pragma unroll
    for (int j = 0; j < RNN_DIM / 128; ++j)
        q_s[tid + 128 * j] = query[b * RNN_DIM + tid + 128 * j];
    __syncthreads();
    const int a = tid;
    const float4* w4 = reinterpret_cast<const float4*>(Wq + a * RNN_DIM);
    float acc = 0.f;
    #pragma unroll 4
    for (int r4 = 0; r4 < RNN_DIM / 4; ++r4) {
        float4 w = w4[r4];
        acc += w.x * q_s[4 * r4 + 0] + w.y * q_s[4 * r4 + 1]
             + w.z * q_s[4 * r4 + 2] + w.w * q_s[4 * r4 + 3];
    }
    pq[b * ATT_DIM + a] = acc;
}

// ------- Kernel B: fused conv + loc projection + tanh + v-dot + mask ------
__global__ __launch_bounds__(256) void k_energy(
    const float* __restrict__ att,   // [B,2,T]
    const float* __restrict__ pm,    // [B,T,128]
    const float* __restrict__ cw,    // [32,2,31]
    const float* __restrict__ Wl,    // [128,32]
    const float* __restrict__ v,     // [128]
    const float* __restrict__ pq,    // [B,128]
    const int*   __restrict__ mask,  // [B,T] (bool -> int32)
    float* __restrict__ energy)      // [B,T]
{
    __shared__ float att_s[2][TT + KSIZE - 1];        // 2 x 94
    __shared__ float loc_s[N_FILT][TT];               // 32 x 64
    __shared__ float pm_s[TT * (ATT_DIM + 1)];        // 64 x 129 (pad->free banks)
    __shared__ float ep_s[4][TT];

    const int b   = blockIdx.y;
    const int t0  = blockIdx.x * TT;
    const int tid = threadIdx.x;
    const int lane = tid & 63;
    const int w    = __builtin_amdgcn_readfirstlane(tid >> 6);

    // stage conv input window (zero padded at edges)
    if (tid < 2 * (TT + KSIZE - 1)) {
        int c = tid / (TT + KSIZE - 1);
        int i = tid % (TT + KSIZE - 1);
        int gt = t0 + i - PAD_;
        att_s[c][i] = (gt >= 0 && gt < T_) ? att[(b * 2 + c) * T_ + gt] : 0.f;
    }
    // stage pm tile, coalesced global read, conflict-free LDS write
    {
        const float* src = pm + ((size_t)b * T_ + t0) * ATT_DIM;
        #pragma unroll
        for (int j = 0; j < TT * ATT_DIM / 256; ++j) {
            int idx = tid + 256 * j;
            int row = idx >> 7, col = idx & 127;
            pm_s[row * (ATT_DIM + 1) + col] = src[idx];
        }
    }
    __syncthreads();

    // conv: wave w computes f in [8w, 8w+8), 4-way f-blocking so each
    // att_s read feeds 4 FMAs; conv weights are wave-uniform -> s_load
    #pragma unroll
    for (int p = 0; p < 2; ++p) {
        int fb = __builtin_amdgcn_readfirstlane(w * 8 + p * 4);
        float a0 = 0.f, a1 = 0.f, a2 = 0.f, a3 = 0.f;
        #pragma unroll
        for (int c = 0; c < 2; ++c) {
            #pragma unroll
            for (int k = 0; k < KSIZE; ++k) {
                float av = att_s[c][lane + k];
                a0 += av * cw[((fb + 0) * 2 + c) * KSIZE + k];
                a1 += av * cw[((fb + 1) * 2 + c) * KSIZE + k];
                a2 += av * cw[((fb + 2) * 2 + c) * KSIZE + k];
                a3 += av * cw[((fb + 3) * 2 + c) * KSIZE + k];
            }
        }
        loc_s[fb + 0][lane] = a0;
        loc_s[fb + 1][lane] = a1;
        loc_s[fb + 2][lane] = a2;
        loc_s[fb + 3][lane] = a3;
    }
    __syncthreads();

    // stage 2: lane = t, loc row in registers; wave w covers a in [32w,32w+32)
    float lreg[N_FILT];
    #pragma unroll
    for (int f = 0; f < N_FILT; ++f) lreg[f] = loc_s[f][lane];

    float eacc = 0.f;
    const int abase = __builtin_amdgcn_readfirstlane(w * 32);
    for (int j = 0; j < 32; ++j) {
        int a = abase + j;
        float pl = 0.f;
        #pragma unroll
        for (int f = 0; f < N_FILT; ++f)
            pl += Wl[a * N_FILT + f] * lreg[f];   // uniform -> SGPR operand
        float x = pl + pm_s[lane * (ATT_DIM + 1) + a] + pq[b * ATT_DIM + a];
        eacc += fast_tanh(x) * v[a];
    }
    ep_s[w][lane] = eacc;
    __syncthreads();
    if (tid < TT) {
        float e = ep_s[0][tid] + ep_s[1][tid] + ep_s[2][tid] + ep_s[3][tid];
        int t = t0 + tid;
        if (mask[b * T_ + t] != 0) e = -INFINITY;
        energy[b * T_ + t] = e;
    }
}

// ---------------- Kernel C: in-place masked softmax over T ----------------
__global__ __launch_bounds__(256) void k_softmax(float* __restrict__ E) {
    const int b = blockIdx.x, tid = threadIdx.x;
    __shared__ float red_s[4];
    float vals[8];
    float m = -INFINITY;
    #pragma unroll
    for (int j = 0; j < 8; ++j) {
        vals[j] = E[b * T_ + tid + 256 * j];
        m = fmaxf(m, vals[j]);
    }
    #pragma unroll
    for (int off = 32; off >= 1; off >>= 1)
        m = fmaxf(m, __shfl_xor(m, off, 64));
    const int w = tid >> 6;
    if ((tid & 63) == 0) red_s[w] = m;
    __syncthreads();
    m = fmaxf(fmaxf(red_s[0], red_s[1]), fmaxf(red_s[2], red_s[3]));
    __syncthreads();
    float s = 0.f;
    #pragma unroll
    for (int j = 0; j < 8; ++j) {
        float p = __expf(vals[j] - m);   // exp(-inf - m) = 0 for masked
        vals[j] = p;
        s += p;
    }
    #pragma unroll
    for (int off = 32; off >= 1; off >>= 1)
        s += __shfl_xor(s, off, 64);
    if ((tid & 63) == 0) red_s[w] = s;
    __syncthreads();
    s = red_s[0] + red_s[1] + red_s[2] + red_s[3];
    float inv = 1.0f / s;
    #pragma unroll
    for (int j = 0; j < 8; ++j)
        E[b * T_ + tid + 256 * j] = vals[j] * inv;
}

// -------- Kernel D: partial context over a 128-t slice (float4 loads) -----
__global__ __launch_bounds__(128) void k_ctx_partial(
    const float* __restrict__ W,    // [B,T] softmaxed weights
    const float* __restrict__ mem,  // [B,T,512]
    float* __restrict__ part)       // [B,16,512]
{
    const int ts = blockIdx.x, b = blockIdx.y, tid = threadIdx.x;
    const int t0 = ts * (T_ / 16);
    const float4* m4 = reinterpret_cast<const float4*>(mem)
                     + ((size_t)b * T_ + t0) * (EMB_DIM / 4);
    float4 acc = make_float4(0.f, 0.f, 0.f, 0.f);
    #pragma unroll 4
    for (int t = 0; t < T_ / 16; ++t) {
        float wt = W[b * T_ + t0 + t];               // uniform -> s_load
        float4 mv = m4[(size_t)t * (EMB_DIM / 4) + tid];
        acc.x += wt * mv.x; acc.y += wt * mv.y;
        acc.z += wt * mv.z; acc.w += wt * mv.w;
    }
    reinterpret_cast<float4*>(part)[((size_t)b * 16 + ts) * (EMB_DIM / 4) + tid] = acc;
}

// ---------------- Kernel E: reduce the 16 partials ------------------------
__global__ __launch_bounds__(256) void k_ctx_reduce(
    const float* __restrict__ part, float* __restrict__ ctx)
{
    const int g = blockIdx.x * 256 + threadIdx.x;   // 0..32767
    const int b = g >> 9, d = g & 511;
    float s = 0.f;
    #pragma unroll
    for (int ts = 0; ts < 16; ++ts)
        s += part[((size_t)b * 16 + ts) * EMB_DIM + d];
    ctx[g] = s;
}

extern "C" void kernel_launch(void* const* d_in, const int* in_sizes, int n_in,
                              void* d_out, int out_size, void* d_ws, size_t ws_size,
                              hipStream_t stream) {
    const float* query = (const float*)d_in[0];
    const float* pm    = (const float*)d_in[1];
    const float* att   = (const float*)d_in[2];
    const int*   mask  = (const int*)d_in[3];
    const float* mem   = (const float*)d_in[4];
    const float* Wq    = (const float*)d_in[5];
    const float* cw    = (const float*)d_in[6];
    const float* Wl    = (const float*)d_in[7];
    const float* vw    = (const float*)d_in[8];

    float* ctx = (float*)d_out;                  // [64,512]   output 0
    float* wts = (float*)d_out + B_ * EMB_DIM;   // [64,2048]  output 1 (energies in-place)
    float* pq   = (float*)d_ws;                  // 8192 floats
    float* part = (float*)d_ws + B_ * ATT_DIM;   // 64*16*512 floats (2 MB)

    k_pq        <<<dim3(B_),        dim3(128), 0, stream>>>(query, Wq, pq);
    k_energy    <<<dim3(T_/TT, B_), dim3(256), 0, stream>>>(att, pm, cw, Wl, vw, pq, mask, wts);
    k_softmax   <<<dim3(B_),        dim3(256), 0, stream>>>(wts);
    k_ctx_partial<<<dim3(16, B_),   dim3(128), 0, stream>>>(wts, mem, part);
    k_ctx_reduce<<<dim3(B_*EMB_DIM/256), dim3(256), 0, stream>>>(part, ctx);
}

// Round 2
// 481.096 us; speedup vs baseline: 1.0037x; 1.0037x over previous
//
#include <hip/hip_runtime.h>
#include <math.h>

#define B_ 64
#define T_ 2048
#define RNN_DIM 1024
#define EMB_DIM 512
#define ATT_DIM 128
#define N_FILT 32
#define KSIZE 31
#define PAD_ 15
#define TT 64           // t-tile for the energy kernel
#define NSLICE 32       // t-slices for the context kernel

__device__ __forceinline__ float fast_tanh(float x) {
    // 1 - 2/(e^{2x}+1); exact at +-inf saturation, ~1e-7 abs err
    float e = __expf(2.0f * x);
    return 1.0f - 2.0f / (e + 1.0f);
}

// ---------------- Kernel A: pq[b,a] = sum_r query[b,r] * Wq[a,r] ----------
__global__ __launch_bounds__(128) void k_pq(const float* __restrict__ query,
                                            const float* __restrict__ Wq,
                                            float* __restrict__ pq) {
    __shared__ float q_s[RNN_DIM];
    const int b = blockIdx.x;
    const int tid = threadIdx.x; // 128
    #pragma unroll
    for (int j = 0; j < RNN_DIM / 128; ++j)
        q_s[tid + 128 * j] = query[b * RNN_DIM + tid + 128 * j];
    __syncthreads();
    const int a = tid;
    const float4* w4 = reinterpret_cast<const float4*>(Wq + a * RNN_DIM);
    float acc = 0.f;
    #pragma unroll 4
    for (int r4 = 0; r4 < RNN_DIM / 4; ++r4) {
        float4 w = w4[r4];
        acc += w.x * q_s[4 * r4 + 0] + w.y * q_s[4 * r4 + 1]
             + w.z * q_s[4 * r4 + 2] + w.w * q_s[4 * r4 + 3];
    }
    pq[b * ATT_DIM + a] = acc;
}

// ------- Kernel B: fused conv + loc projection + tanh + v-dot + mask ------
__global__ __launch_bounds__(256) void k_energy(
    const float* __restrict__ att,   // [B,2,T]
    const float* __restrict__ pm,    // [B,T,128]
    const float* __restrict__ cw,    // [32,2,31]
    const float* __restrict__ Wl,    // [128,32]
    const float* __restrict__ v,     // [128]
    const float* __restrict__ pq,    // [B,128]
    const int*   __restrict__ mask,  // [B,T] (bool -> int32)
    float* __restrict__ energy)      // [B,T]
{
    __shared__ float att_s[2][TT + KSIZE - 1];        // 2 x 94
    __shared__ float loc_s[N_FILT][TT];               // 32 x 64
    __shared__ float pm_s[TT * (ATT_DIM + 1)];        // 64 x 129 (pad->free banks)
    __shared__ float ep_s[4][TT];

    const int b   = blockIdx.y;
    const int t0  = blockIdx.x * TT;
    const int tid = threadIdx.x;
    const int lane = tid & 63;
    const int w    = __builtin_amdgcn_readfirstlane(tid >> 6);

    // stage conv input window (zero padded at edges)
    if (tid < 2 * (TT + KSIZE - 1)) {
        int c = tid / (TT + KSIZE - 1);
        int i = tid % (TT + KSIZE - 1);
        int gt = t0 + i - PAD_;
        att_s[c][i] = (gt >= 0 && gt < T_) ? att[(b * 2 + c) * T_ + gt] : 0.f;
    }
    // stage pm tile, coalesced global read, conflict-free LDS write
    {
        const float* src = pm + ((size_t)b * T_ + t0) * ATT_DIM;
        #pragma unroll
        for (int j = 0; j < TT * ATT_DIM / 256; ++j) {
            int idx = tid + 256 * j;
            int row = idx >> 7, col = idx & 127;
            pm_s[row * (ATT_DIM + 1) + col] = src[idx];
        }
    }
    __syncthreads();

    // conv: wave w computes f in [8w, 8w+8), 4-way f-blocking so each
    // att_s read feeds 4 FMAs; conv weights are wave-uniform -> s_load
    #pragma unroll
    for (int p = 0; p < 2; ++p) {
        int fb = __builtin_amdgcn_readfirstlane(w * 8 + p * 4);
        float a0 = 0.f, a1 = 0.f, a2 = 0.f, a3 = 0.f;
        #pragma unroll
        for (int c = 0; c < 2; ++c) {
            #pragma unroll
            for (int k = 0; k < KSIZE; ++k) {
                float av = att_s[c][lane + k];
                a0 += av * cw[((fb + 0) * 2 + c) * KSIZE + k];
                a1 += av * cw[((fb + 1) * 2 + c) * KSIZE + k];
                a2 += av * cw[((fb + 2) * 2 + c) * KSIZE + k];
                a3 += av * cw[((fb + 3) * 2 + c) * KSIZE + k];
            }
        }
        loc_s[fb + 0][lane] = a0;
        loc_s[fb + 1][lane] = a1;
        loc_s[fb + 2][lane] = a2;
        loc_s[fb + 3][lane] = a3;
    }
    __syncthreads();

    // stage 2: lane = t, loc row in registers; wave w covers a in [32w,32w+32)
    float lreg[N_FILT];
    #pragma unroll
    for (int f = 0; f < N_FILT; ++f) lreg[f] = loc_s[f][lane];

    const float* pm_row = pm_s + lane * (ATT_DIM + 1);
    const float* pq_row = pq + b * ATT_DIM;
    float eacc = 0.f;
    const int abase = __builtin_amdgcn_readfirstlane(w * 32);
    #pragma unroll 2
    for (int j = 0; j < 32; ++j) {
        int a = abase + j;
        const float* wl_row = Wl + a * N_FILT;   // uniform -> s_load
        float pl = 0.f;
        #pragma unroll
        for (int f = 0; f < N_FILT; ++f)
            pl += wl_row[f] * lreg[f];
        float x = pl + pm_row[a] + pq_row[a];
        eacc += fast_tanh(x) * v[a];
    }
    ep_s[w][lane] = eacc;
    __syncthreads();
    if (tid < TT) {
        float e = ep_s[0][tid] + ep_s[1][tid] + ep_s[2][tid] + ep_s[3][tid];
        int t = t0 + tid;
        if (mask[b * T_ + t] != 0) e = -INFINITY;
        energy[b * T_ + t] = e;
    }
}

// ---------------- Kernel C: in-place masked softmax over T ----------------
__global__ __launch_bounds__(512) void k_softmax(float* __restrict__ E) {
    const int b = blockIdx.x, tid = threadIdx.x;   // 512 threads, 4 elems each
    __shared__ float red_s[8];
    float vals[4];
    float m = -INFINITY;
    #pragma unroll
    for (int j = 0; j < 4; ++j) {
        vals[j] = E[b * T_ + tid + 512 * j];
        m = fmaxf(m, vals[j]);
    }
    #pragma unroll
    for (int off = 32; off >= 1; off >>= 1)
        m = fmaxf(m, __shfl_xor(m, off, 64));
    const int w = tid >> 6;
    if ((tid & 63) == 0) red_s[w] = m;
    __syncthreads();
    m = red_s[0];
    #pragma unroll
    for (int i = 1; i < 8; ++i) m = fmaxf(m, red_s[i]);
    __syncthreads();
    float s = 0.f;
    #pragma unroll
    for (int j = 0; j < 4; ++j) {
        float p = __expf(vals[j] - m);   // exp(-inf - m) = 0 for masked
        vals[j] = p;
        s += p;
    }
    #pragma unroll
    for (int off = 32; off >= 1; off >>= 1)
        s += __shfl_xor(s, off, 64);
    if ((tid & 63) == 0) red_s[w] = s;
    __syncthreads();
    s = red_s[0];
    #pragma unroll
    for (int i = 1; i < 8; ++i) s += red_s[i];
    float inv = 1.0f / s;
    #pragma unroll
    for (int j = 0; j < 4; ++j)
        E[b * T_ + tid + 512 * j] = vals[j] * inv;
}

// -------- Kernel D: partial context over a 64-t slice (float4 loads) ------
__global__ __launch_bounds__(128) void k_ctx_partial(
    const float* __restrict__ W,    // [B,T] softmaxed weights
    const float* __restrict__ mem,  // [B,T,512]
    float* __restrict__ part)       // [B,32,512]
{
    const int ts = blockIdx.x, b = blockIdx.y, tid = threadIdx.x;
    const int t0 = ts * (T_ / NSLICE);
    const float4* m4 = reinterpret_cast<const float4*>(mem)
                     + ((size_t)b * T_ + t0) * (EMB_DIM / 4);
    float4 acc = make_float4(0.f, 0.f, 0.f, 0.f);
    #pragma unroll 8
    for (int t = 0; t < T_ / NSLICE; ++t) {
        float wt = W[b * T_ + t0 + t];               // uniform -> s_load
        float4 mv = m4[(size_t)t * (EMB_DIM / 4) + tid];
        acc.x += wt * mv.x; acc.y += wt * mv.y;
        acc.z += wt * mv.z; acc.w += wt * mv.w;
    }
    reinterpret_cast<float4*>(part)[((size_t)b * NSLICE + ts) * (EMB_DIM / 4) + tid] = acc;
}

// ---------------- Kernel E: reduce the 32 partials ------------------------
__global__ __launch_bounds__(256) void k_ctx_reduce(
    const float* __restrict__ part, float* __restrict__ ctx)
{
    const int g = blockIdx.x * 256 + threadIdx.x;   // 0..32767
    const int b = g >> 9, d = g & 511;
    float s = 0.f;
    #pragma unroll
    for (int ts = 0; ts < NSLICE; ++ts)
        s += part[((size_t)b * NSLICE + ts) * EMB_DIM + d];
    ctx[g] = s;
}

extern "C" void kernel_launch(void* const* d_in, const int* in_sizes, int n_in,
                              void* d_out, int out_size, void* d_ws, size_t ws_size,
                              hipStream_t stream) {
    const float* query = (const float*)d_in[0];
    const float* pm    = (const float*)d_in[1];
    const float* att   = (const float*)d_in[2];
    const int*   mask  = (const int*)d_in[3];
    const float* mem   = (const float*)d_in[4];
    const float* Wq    = (const float*)d_in[5];
    const float* cw    = (const float*)d_in[6];
    const float* Wl    = (const float*)d_in[7];
    const float* vw    = (const float*)d_in[8];

    float* ctx = (float*)d_out;                  // [64,512]   output 0
    float* wts = (float*)d_out + B_ * EMB_DIM;   // [64,2048]  output 1 (energies in-place)
    float* pq   = (float*)d_ws;                  // 8192 floats
    float* part = (float*)d_ws + B_ * ATT_DIM;   // 64*32*512 floats (4 MB)

    k_pq        <<<dim3(B_),        dim3(128), 0, stream>>>(query, Wq, pq);
    k_energy    <<<dim3(T_/TT, B_), dim3(256), 0, stream>>>(att, pm, cw, Wl, vw, pq, mask, wts);
    k_softmax   <<<dim3(B_),        dim3(512), 0, stream>>>(wts);
    k_ctx_partial<<<dim3(NSLICE, B_), dim3(128), 0, stream>>>(wts, mem, part);
    k_ctx_reduce<<<dim3(B_*EMB_DIM/256), dim3(256), 0, stream>>>(part, ctx);
}

// Round 4
// 480.164 us; speedup vs baseline: 1.0057x; 1.0019x over previous
//
#include <hip/hip_runtime.h>
#include <math.h>

#define B_ 64
#define T_ 2048
#define RNN_DIM 1024
#define EMB_DIM 512
#define ATT_DIM 128
#define N_FILT 32
#define KSIZE 31
#define PAD_ 15
#define TT 64           // t-tile for the energy kernel
#define NSLICE 32       // t-slices for the context kernel

__device__ __forceinline__ float fast_tanh(float x) {
    // 1 - 2/(e^{2x}+1); exact at +-inf saturation, ~1e-7 abs err
    float e = __expf(2.0f * x);
    return 1.0f - 2.0f / (e + 1.0f);
}

// ---------------- Kernel A: pq[b,a] = sum_r query[b,r] * Wq[a,r] ----------
__global__ __launch_bounds__(128) void k_pq(const float* __restrict__ query,
                                            const float* __restrict__ Wq,
                                            float* __restrict__ pq) {
    __shared__ float q_s[RNN_DIM];
    const int b = blockIdx.x;
    const int tid = threadIdx.x; // 128
    #pragma unroll
    for (int j = 0; j < RNN_DIM / 128; ++j)
        q_s[tid + 128 * j] = query[b * RNN_DIM + tid + 128 * j];
    __syncthreads();
    const int a = tid;
    const float4* w4 = reinterpret_cast<const float4*>(Wq + a * RNN_DIM);
    float acc = 0.f;
    #pragma unroll 4
    for (int r4 = 0; r4 < RNN_DIM / 4; ++r4) {
        float4 w = w4[r4];
        acc += w.x * q_s[4 * r4 + 0] + w.y * q_s[4 * r4 + 1]
             + w.z * q_s[4 * r4 + 2] + w.w * q_s[4 * r4 + 3];
    }
    pq[b * ATT_DIM + a] = acc;
}

// ------- Kernel B: fused conv + loc projection + tanh + v-dot + mask ------
__global__ __launch_bounds__(256) void k_energy(
    const float* __restrict__ att,   // [B,2,T]
    const float* __restrict__ pm,    // [B,T,128]
    const float* __restrict__ cw,    // [32,2,31]
    const float* __restrict__ Wl,    // [128,32]
    const float* __restrict__ v,     // [128]
    const float* __restrict__ pq,    // [B,128]
    const int*   __restrict__ mask,  // [B,T] (bool -> int32)
    float* __restrict__ energy)      // [B,T]
{
    __shared__ float att_s[2][TT + KSIZE - 1];        // 2 x 94
    __shared__ float loc_s[N_FILT][TT];               // 32 x 64
    __shared__ float pm_s[TT * (ATT_DIM + 1)];        // 64 x 129 (pad->free banks)
    __shared__ float ep_s[4][TT];

    const int b   = blockIdx.y;
    const int t0  = blockIdx.x * TT;
    const int tid = threadIdx.x;
    const int lane = tid & 63;
    const int w    = __builtin_amdgcn_readfirstlane(tid >> 6);

    // stage conv input window (zero padded at edges)
    if (tid < 2 * (TT + KSIZE - 1)) {
        int c = tid / (TT + KSIZE - 1);
        int i = tid % (TT + KSIZE - 1);
        int gt = t0 + i - PAD_;
        att_s[c][i] = (gt >= 0 && gt < T_) ? att[(b * 2 + c) * T_ + gt] : 0.f;
    }
    // stage pm tile, coalesced global read, conflict-free LDS write
    {
        const float* src = pm + ((size_t)b * T_ + t0) * ATT_DIM;
        #pragma unroll
        for (int j = 0; j < TT * ATT_DIM / 256; ++j) {
            int idx = tid + 256 * j;
            int row = idx >> 7, col = idx & 127;
            pm_s[row * (ATT_DIM + 1) + col] = src[idx];
        }
    }
    __syncthreads();

    // conv: wave w computes f in [8w, 8w+8), 4-way f-blocking so each
    // att_s read feeds 4 FMAs; conv weights are wave-uniform -> s_load
    #pragma unroll
    for (int p = 0; p < 2; ++p) {
        int fb = __builtin_amdgcn_readfirstlane(w * 8 + p * 4);
        float a0 = 0.f, a1 = 0.f, a2 = 0.f, a3 = 0.f;
        #pragma unroll
        for (int c = 0; c < 2; ++c) {
            #pragma unroll
            for (int k = 0; k < KSIZE; ++k) {
                float av = att_s[c][lane + k];
                a0 += av * cw[((fb + 0) * 2 + c) * KSIZE + k];
                a1 += av * cw[((fb + 1) * 2 + c) * KSIZE + k];
                a2 += av * cw[((fb + 2) * 2 + c) * KSIZE + k];
                a3 += av * cw[((fb + 3) * 2 + c) * KSIZE + k];
            }
        }
        loc_s[fb + 0][lane] = a0;
        loc_s[fb + 1][lane] = a1;
        loc_s[fb + 2][lane] = a2;
        loc_s[fb + 3][lane] = a3;
    }
    __syncthreads();

    // stage 2: lane = t, loc row in registers; wave w covers a in [32w,32w+32)
    float lreg[N_FILT];
    #pragma unroll
    for (int f = 0; f < N_FILT; ++f) lreg[f] = loc_s[f][lane];

    const float* pm_row = pm_s + lane * (ATT_DIM + 1);
    const float* pq_row = pq + b * ATT_DIM;
    float eacc = 0.f;
    const int abase = __builtin_amdgcn_readfirstlane(w * 32);
    #pragma unroll 2
    for (int j = 0; j < 32; ++j) {
        int a = abase + j;
        const float* wl_row = Wl + a * N_FILT;   // uniform -> s_load
        float pl = 0.f;
        #pragma unroll
        for (int f = 0; f < N_FILT; ++f)
            pl += wl_row[f] * lreg[f];
        float x = pl + pm_row[a] + pq_row[a];
        eacc += fast_tanh(x) * v[a];
    }
    ep_s[w][lane] = eacc;
    __syncthreads();
    if (tid < TT) {
        float e = ep_s[0][tid] + ep_s[1][tid] + ep_s[2][tid] + ep_s[3][tid];
        int t = t0 + tid;
        if (mask[b * T_ + t] != 0) e = -INFINITY;
        energy[b * T_ + t] = e;
    }
}

// ---------------- Kernel C: in-place masked softmax over T ----------------
__global__ __launch_bounds__(512) void k_softmax(float* __restrict__ E) {
    const int b = blockIdx.x, tid = threadIdx.x;   // 512 threads, 4 elems each
    __shared__ float red_s[8];
    float vals[4];
    float m = -INFINITY;
    #pragma unroll
    for (int j = 0; j < 4; ++j) {
        vals[j] = E[b * T_ + tid + 512 * j];
        m = fmaxf(m, vals[j]);
    }
    #pragma unroll
    for (int off = 32; off >= 1; off >>= 1)
        m = fmaxf(m, __shfl_xor(m, off, 64));
    const int w = tid >> 6;
    if ((tid & 63) == 0) red_s[w] = m;
    __syncthreads();
    m = red_s[0];
    #pragma unroll
    for (int i = 1; i < 8; ++i) m = fmaxf(m, red_s[i]);
    __syncthreads();
    float s = 0.f;
    #pragma unroll
    for (int j = 0; j < 4; ++j) {
        float p = __expf(vals[j] - m);   // exp(-inf - m) = 0 for masked
        vals[j] = p;
        s += p;
    }
    #pragma unroll
    for (int off = 32; off >= 1; off >>= 1)
        s += __shfl_xor(s, off, 64);
    if ((tid & 63) == 0) red_s[w] = s;
    __syncthreads();
    s = red_s[0];
    #pragma unroll
    for (int i = 1; i < 8; ++i) s += red_s[i];
    float inv = 1.0f / s;
    #pragma unroll
    for (int j = 0; j < 4; ++j)
        E[b * T_ + tid + 512 * j] = vals[j] * inv;
}

// -------- Kernel D: partial context over a 64-t slice (float4 loads) ------
__global__ __launch_bounds__(128) void k_ctx_partial(
    const float* __restrict__ W,    // [B,T] softmaxed weights
    const float* __restrict__ mem,  // [B,T,512]
    float* __restrict__ part)       // [B,32,512]
{
    const int ts = blockIdx.x, b = blockIdx.y, tid = threadIdx.x;
    const int t0 = ts * (T_ / NSLICE);
    const float4* m4 = reinterpret_cast<const float4*>(mem)
                     + ((size_t)b * T_ + t0) * (EMB_DIM / 4);
    float4 acc = make_float4(0.f, 0.f, 0.f, 0.f);
    #pragma unroll 8
    for (int t = 0; t < T_ / NSLICE; ++t) {
        float wt = W[b * T_ + t0 + t];               // uniform -> s_load
        float4 mv = m4[(size_t)t * (EMB_DIM / 4) + tid];
        acc.x += wt * mv.x; acc.y += wt * mv.y;
        acc.z += wt * mv.z; acc.w += wt * mv.w;
    }
    reinterpret_cast<float4*>(part)[((size_t)b * NSLICE + ts) * (EMB_DIM / 4) + tid] = acc;
}

// ---------------- Kernel E: reduce the 32 partials ------------------------
__global__ __launch_bounds__(256) void k_ctx_reduce(
    const float* __restrict__ part, float* __restrict__ ctx)
{
    const int g = blockIdx.x * 256 + threadIdx.x;   // 0..32767
    const int b = g >> 9, d = g & 511;
    float s = 0.f;
    #pragma unroll
    for (int ts = 0; ts < NSLICE; ++ts)
        s += part[((size_t)b * NSLICE + ts) * EMB_DIM + d];
    ctx[g] = s;
}

extern "C" void kernel_launch(void* const* d_in, const int* in_sizes, int n_in,
                              void* d_out, int out_size, void* d_ws, size_t ws_size,
                              hipStream_t stream) {
    const float* query = (const float*)d_in[0];
    const float* pm    = (const float*)d_in[1];
    const float* att   = (const float*)d_in[2];
    const int*   mask  = (const int*)d_in[3];
    const float* mem   = (const float*)d_in[4];
    const float* Wq    = (const float*)d_in[5];
    const float* cw    = (const float*)d_in[6];
    const float* Wl    = (const float*)d_in[7];
    const float* vw    = (const float*)d_in[8];

    float* ctx = (float*)d_out;                  // [64,512]   output 0
    float* wts = (float*)d_out + B_ * EMB_DIM;   // [64,2048]  output 1 (energies in-place)
    float* pq   = (float*)d_ws;                  // 8192 floats
    float* part = (float*)d_ws + B_ * ATT_DIM;   // 64*32*512 floats (4 MB)

    k_pq        <<<dim3(B_),        dim3(128), 0, stream>>>(query, Wq, pq);
    k_energy    <<<dim3(T_/TT, B_), dim3(256), 0, stream>>>(att, pm, cw, Wl, vw, pq, mask, wts);
    k_softmax   <<<dim3(B_),        dim3(512), 0, stream>>>(wts);
    k_ctx_partial<<<dim3(NSLICE, B_), dim3(128), 0, stream>>>(wts, mem, part);
    k_ctx_reduce<<<dim3(B_*EMB_DIM/256), dim3(256), 0, stream>>>(part, ctx);
}